// Round 1
// baseline (17302.829 us; speedup 1.0000x reference)
//
#include <hip/hip_runtime.h>

// GNN fused forward, fp32, one wave (64 lanes) per graph, grid-stride.
// B=65536 graphs, N=5, E=8, D=128, DE=32, L=4, PD=256, M1=256, M2=64.

constexpr int NB  = 65536;
constexpr int NN  = 5;
constexpr int NE  = 8;
constexpr int NFD = 7;
constexpr int EFD = 2;
constexpr int D_  = 128;
constexpr int DE_ = 32;
constexpr int L_  = 4;
constexpr int PD_ = 256;
constexpr int M2_ = 64;

__device__ __forceinline__ float lrelu(float v) { return v >= 0.f ? v : 0.01f * v; }

// per-wave LDS layout (floats)
constexpr int WS_X   = 0;              // 5*128 = 640
constexpr int WS_EA  = 640;            // 8*32  = 256
constexpr int WS_M1  = 896;            // 8*128 = 1024  (reused as p/q buf after layers)
constexpr int WS_M2  = 1920;           // 8*128 = 1024  (aliased with u1 5*128)
constexpr int WS_AGG = 2944;           // 5*128 = 640
constexpr int WS_TOT = 3584;           // floats = 14336 B / wave

__global__ __launch_bounds__(256, 2)
void gnn_fused(const float* __restrict__ node_feat,
               const float* __restrict__ edge_feat,
               const int*   __restrict__ edge_index_raw,
               const float* __restrict__ node_w,  const float* __restrict__ node_b,
               const float* __restrict__ edge_w,  const float* __restrict__ edge_b,
               const float* __restrict__ msg_w1,  const float* __restrict__ msg_b1,
               const float* __restrict__ msg_w2,  const float* __restrict__ msg_b2,
               const float* __restrict__ upd_w1,  const float* __restrict__ upd_b1,
               const float* __restrict__ upd_g1,  const float* __restrict__ upd_be1,
               const float* __restrict__ upd_w2,  const float* __restrict__ upd_b2,
               const float* __restrict__ upd_g2,  const float* __restrict__ upd_be2,
               const float* __restrict__ pool_w,  const float* __restrict__ pool_b,
               const float* __restrict__ pool_g,  const float* __restrict__ pool_be,
               const float* __restrict__ mlp1_w,  const float* __restrict__ mlp1_b,
               const float* __restrict__ mlp1_g,  const float* __restrict__ mlp1_be,
               const float* __restrict__ mlp2_w,  const float* __restrict__ mlp2_b,
               const float* __restrict__ mlp2_g,  const float* __restrict__ mlp2_be,
               float* __restrict__ out)
{
    __shared__ float lds[4 * WS_TOT];
    const int tid  = threadIdx.x;
    const int wave = tid >> 6;
    const int lane = tid & 63;
    float* ws  = lds + wave * WS_TOT;
    float* xs  = ws + WS_X;
    float* eas = ws + WS_EA;
    float* m1  = ws + WS_M1;
    float* m2  = ws + WS_M2;   // also u1
    float* agg = ws + WS_AGG;

    // Robust edge_index decode: int64 (odd 32-bit words all zero, values 0..4)
    // vs int32. JAX without x64 yields int32; handle both.
    int srcl[NE], dstl[NE];
    {
        bool is64 = true;
        #pragma unroll
        for (int i = 1; i < 16; i += 2) if (edge_index_raw[i] != 0) is64 = false;
        #pragma unroll
        for (int e = 0; e < NE; ++e) {
            if (is64) { srcl[e] = edge_index_raw[2*e]; dstl[e] = edge_index_raw[16 + 2*e]; }
            else      { srcl[e] = edge_index_raw[e];   dstl[e] = edge_index_raw[8 + e];   }
        }
    }

    const int c0 = lane, c1 = lane + 64;
    const int gw_total = (gridDim.x * blockDim.x) >> 6;
    const int gw = (blockIdx.x * blockDim.x + tid) >> 6;

    for (int g = gw; g < NB; g += gw_total) {
        const float* nf = node_feat + (size_t)g * (NN * NFD);
        const float* ef = edge_feat + (size_t)g * (NE * EFD);

        // ---- encoders ----
        #pragma unroll
        for (int i = 0; i < 10; ++i) {
            int idx = lane + i * 64;
            int n = idx >> 7, c = idx & 127;
            float acc = node_b[c];
            #pragma unroll
            for (int k = 0; k < NFD; ++k)
                acc += nf[n * NFD + k] * node_w[k * D_ + c];
            xs[n * D_ + c] = acc;
        }
        #pragma unroll
        for (int i = 0; i < 4; ++i) {
            int idx = lane + i * 64;
            int e = idx >> 5, c = idx & 31;
            float acc = edge_b[c] + ef[e*EFD+0]*edge_w[c] + ef[e*EFD+1]*edge_w[DE_ + c];
            eas[e * DE_ + c] = acc;
        }
        __syncthreads();

        // ---- message-passing layers ----
        for (int l = 0; l < L_; ++l) {
            // m = lrelu([x[dst], x[src], ea] @ msg_w1 + b1)
            {
                float acc0[NE], acc1[NE];
                const float b0 = msg_b1[l*D_ + c0], b1 = msg_b1[l*D_ + c1];
                #pragma unroll
                for (int e = 0; e < NE; ++e) { acc0[e] = b0; acc1[e] = b1; }
                const float* W = msg_w1 + (size_t)l * 288 * D_;
                #pragma unroll 4
                for (int k = 0; k < D_; ++k) {
                    float w0 = W[k*D_ + c0], w1 = W[k*D_ + c1];
                    #pragma unroll
                    for (int e = 0; e < NE; ++e) {
                        float a = xs[dstl[e]*D_ + k];
                        acc0[e] += a * w0; acc1[e] += a * w1;
                    }
                }
                const float* Ws = W + 128 * D_;
                #pragma unroll 4
                for (int k = 0; k < D_; ++k) {
                    float w0 = Ws[k*D_ + c0], w1 = Ws[k*D_ + c1];
                    #pragma unroll
                    for (int e = 0; e < NE; ++e) {
                        float a = xs[srcl[e]*D_ + k];
                        acc0[e] += a * w0; acc1[e] += a * w1;
                    }
                }
                const float* We = W + 256 * D_;
                #pragma unroll 4
                for (int k = 0; k < DE_; ++k) {
                    float w0 = We[k*D_ + c0], w1 = We[k*D_ + c1];
                    #pragma unroll
                    for (int e = 0; e < NE; ++e) {
                        float a = eas[e*DE_ + k];
                        acc0[e] += a * w0; acc1[e] += a * w1;
                    }
                }
                #pragma unroll
                for (int e = 0; e < NE; ++e) {
                    m1[e*D_ + c0] = lrelu(acc0[e]);
                    m1[e*D_ + c1] = lrelu(acc1[e]);
                }
            }
            __syncthreads();

            // m = lrelu(m @ msg_w2 + b2)
            {
                float acc0[NE], acc1[NE];
                const float b0 = msg_b2[l*D_ + c0], b1 = msg_b2[l*D_ + c1];
                #pragma unroll
                for (int e = 0; e < NE; ++e) { acc0[e] = b0; acc1[e] = b1; }
                const float* W = msg_w2 + (size_t)l * D_ * D_;
                #pragma unroll 4
                for (int k = 0; k < D_; ++k) {
                    float w0 = W[k*D_ + c0], w1 = W[k*D_ + c1];
                    #pragma unroll
                    for (int e = 0; e < NE; ++e) {
                        float a = m1[e*D_ + k];
                        acc0[e] += a * w0; acc1[e] += a * w1;
                    }
                }
                #pragma unroll
                for (int e = 0; e < NE; ++e) {
                    m2[e*D_ + c0] = lrelu(acc0[e]);
                    m2[e*D_ + c1] = lrelu(acc1[e]);
                }
            }
            __syncthreads();

            // agg[n] = sum_{e: dst[e]==n} m[e]
            #pragma unroll
            for (int i = 0; i < 10; ++i) {
                int idx = lane + i * 64;
                int n = idx >> 7, d = idx & 127;
                float s = 0.f;
                #pragma unroll
                for (int e = 0; e < NE; ++e)
                    s = (dstl[e] == n) ? (s + m2[e*D_ + d]) : s;
                agg[n*D_ + d] = s;
            }
            __syncthreads();

            // u1 = lrelu(([x, agg] @ upd_w1 + b1) * g1[n] + be1[n])  -> stored in m2 space
            {
                float acc0[NN], acc1[NN];
                const float b0 = upd_b1[l*D_ + c0], b1 = upd_b1[l*D_ + c1];
                #pragma unroll
                for (int n = 0; n < NN; ++n) { acc0[n] = b0; acc1[n] = b1; }
                const float* W = upd_w1 + (size_t)l * 256 * D_;
                #pragma unroll 4
                for (int k = 0; k < D_; ++k) {
                    float w0 = W[k*D_ + c0], w1 = W[k*D_ + c1];
                    #pragma unroll
                    for (int n = 0; n < NN; ++n) {
                        float a = xs[n*D_ + k];
                        acc0[n] += a * w0; acc1[n] += a * w1;
                    }
                }
                const float* Ws = W + 128 * D_;
                #pragma unroll 4
                for (int k = 0; k < D_; ++k) {
                    float w0 = Ws[k*D_ + c0], w1 = Ws[k*D_ + c1];
                    #pragma unroll
                    for (int n = 0; n < NN; ++n) {
                        float a = agg[n*D_ + k];
                        acc0[n] += a * w0; acc1[n] += a * w1;
                    }
                }
                #pragma unroll
                for (int n = 0; n < NN; ++n) {
                    float gg = upd_g1[l*NN + n], bb = upd_be1[l*NN + n];
                    m2[n*D_ + c0] = lrelu(acc0[n] * gg + bb);
                    m2[n*D_ + c1] = lrelu(acc1[n] * gg + bb);
                }
            }
            __syncthreads();

            // x += lrelu((u1 @ upd_w2 + b2) * g2[n] + be2[n])
            {
                float acc0[NN], acc1[NN];
                const float b0 = upd_b2[l*D_ + c0], b1 = upd_b2[l*D_ + c1];
                #pragma unroll
                for (int n = 0; n < NN; ++n) { acc0[n] = b0; acc1[n] = b1; }
                const float* W = upd_w2 + (size_t)l * D_ * D_;
                #pragma unroll 4
                for (int k = 0; k < D_; ++k) {
                    float w0 = W[k*D_ + c0], w1 = W[k*D_ + c1];
                    #pragma unroll
                    for (int n = 0; n < NN; ++n) {
                        float a = m2[n*D_ + k];
                        acc0[n] += a * w0; acc1[n] += a * w1;
                    }
                }
                #pragma unroll
                for (int n = 0; n < NN; ++n) {
                    float gg = upd_g2[l*NN + n], bb = upd_be2[l*NN + n];
                    xs[n*D_ + c0] += lrelu(acc0[n] * gg + bb);
                    xs[n*D_ + c1] += lrelu(acc1[n] * gg + bb);
                }
            }
            __syncthreads();
        }

        // ---- pooling MLP ----
        // p = lrelu((x.flat @ pool_w + b) * g + be), 640 -> 256, stored m1[0..255]
        {
            float a0 = pool_b[lane], a1 = pool_b[lane+64],
                  a2 = pool_b[lane+128], a3 = pool_b[lane+192];
            #pragma unroll 4
            for (int k = 0; k < NN*D_; ++k) {
                float a = xs[k];
                const float* wr = pool_w + (size_t)k * PD_;
                a0 += a * wr[lane];      a1 += a * wr[lane+64];
                a2 += a * wr[lane+128];  a3 += a * wr[lane+192];
            }
            m1[lane]     = lrelu(a0 * pool_g[lane]     + pool_be[lane]);
            m1[lane+64]  = lrelu(a1 * pool_g[lane+64]  + pool_be[lane+64]);
            m1[lane+128] = lrelu(a2 * pool_g[lane+128] + pool_be[lane+128]);
            m1[lane+192] = lrelu(a3 * pool_g[lane+192] + pool_be[lane+192]);
        }
        __syncthreads();

        // q = lrelu((p @ mlp1_w + b) * g + be), 256 -> 256, stored m1[256..511]
        {
            float a0 = mlp1_b[lane], a1 = mlp1_b[lane+64],
                  a2 = mlp1_b[lane+128], a3 = mlp1_b[lane+192];
            #pragma unroll 4
            for (int k = 0; k < PD_; ++k) {
                float a = m1[k];
                const float* wr = mlp1_w + (size_t)k * PD_;
                a0 += a * wr[lane];      a1 += a * wr[lane+64];
                a2 += a * wr[lane+128];  a3 += a * wr[lane+192];
            }
            m1[256+lane]     = lrelu(a0 * mlp1_g[lane]     + mlp1_be[lane]);
            m1[256+lane+64]  = lrelu(a1 * mlp1_g[lane+64]  + mlp1_be[lane+64]);
            m1[256+lane+128] = lrelu(a2 * mlp1_g[lane+128] + mlp1_be[lane+128]);
            m1[256+lane+192] = lrelu(a3 * mlp1_g[lane+192] + mlp1_be[lane+192]);
        }
        __syncthreads();

        // r = lrelu((q @ mlp2_w + b) * g + be), 256 -> 64; out = mean(r)
        {
            float acc = mlp2_b[lane];
            #pragma unroll 4
            for (int k = 0; k < PD_; ++k)
                acc += m1[256+k] * mlp2_w[k*M2_ + lane];
            float r = lrelu(acc * mlp2_g[lane] + mlp2_be[lane]);
            #pragma unroll
            for (int off = 32; off >= 1; off >>= 1)
                r += __shfl_xor(r, off);
            if (lane == 0) out[g] = r * (1.f / 64.f);
        }
        __syncthreads();
    }
}

extern "C" void kernel_launch(void* const* d_in, const int* in_sizes, int n_in,
                              void* d_out, int out_size, void* d_ws, size_t ws_size,
                              hipStream_t stream) {
    const float* node_feat = (const float*)d_in[0];
    const float* edge_feat = (const float*)d_in[1];
    const int*   edge_index = (const int*)d_in[2];
    const float* node_w  = (const float*)d_in[3];
    const float* node_b  = (const float*)d_in[4];
    const float* edge_w  = (const float*)d_in[5];
    const float* edge_b  = (const float*)d_in[6];
    const float* msg_w1  = (const float*)d_in[7];
    const float* msg_b1  = (const float*)d_in[8];
    const float* msg_w2  = (const float*)d_in[9];
    const float* msg_b2  = (const float*)d_in[10];
    const float* upd_w1  = (const float*)d_in[11];
    const float* upd_b1  = (const float*)d_in[12];
    const float* upd_g1  = (const float*)d_in[13];
    const float* upd_be1 = (const float*)d_in[14];
    const float* upd_w2  = (const float*)d_in[15];
    const float* upd_b2  = (const float*)d_in[16];
    const float* upd_g2  = (const float*)d_in[17];
    const float* upd_be2 = (const float*)d_in[18];
    const float* pool_w  = (const float*)d_in[19];
    const float* pool_b  = (const float*)d_in[20];
    const float* pool_g  = (const float*)d_in[21];
    const float* pool_be = (const float*)d_in[22];
    const float* mlp1_w  = (const float*)d_in[23];
    const float* mlp1_b  = (const float*)d_in[24];
    const float* mlp1_g  = (const float*)d_in[25];
    const float* mlp1_be = (const float*)d_in[26];
    const float* mlp2_w  = (const float*)d_in[27];
    const float* mlp2_b  = (const float*)d_in[28];
    const float* mlp2_g  = (const float*)d_in[29];
    const float* mlp2_be = (const float*)d_in[30];
    float* out = (float*)d_out;

    // 2048 blocks * 4 waves = 8192 waves; 65536/8192 = 8 graphs per wave.
    gnn_fused<<<2048, 256, 0, stream>>>(
        node_feat, edge_feat, edge_index,
        node_w, node_b, edge_w, edge_b,
        msg_w1, msg_b1, msg_w2, msg_b2,
        upd_w1, upd_b1, upd_g1, upd_be1,
        upd_w2, upd_b2, upd_g2, upd_be2,
        pool_w, pool_b, pool_g, pool_be,
        mlp1_w, mlp1_b, mlp1_g, mlp1_be,
        mlp2_w, mlp2_b, mlp2_g, mlp2_be,
        out);
}

// Round 2
// 1915.552 us; speedup vs baseline: 9.0328x; 9.0328x over previous
//
#include <hip/hip_runtime.h>

// Fused GNN forward with f16 MFMA (fp32 accumulate).
// 16 graphs per block, 512 threads (8 waves). All activations f16 in LDS
// (XOR-swizzled), x-residual fp32 in registers. Weights pre-transposed to
// f16 [N][K] in d_ws by prep kernel.

typedef _Float16 h8 __attribute__((ext_vector_type(8)));
typedef float f4 __attribute__((ext_vector_type(4)));

constexpr int NB = 65536;
constexpr int GG = 16;                 // graphs per block
constexpr int NBLK = NB / GG;          // 4096 blocks

__device__ __forceinline__ float lrelu(float v){ return v >= 0.f ? v : 0.01f*v; }
__device__ __forceinline__ int div5(int v){ return (v*52429)>>18; }  // exact for v<131072

// LDS row stride 128 f16 (256B), XOR-swizzle bits 4-6 by row&7 (bank spread).
__device__ __forceinline__ _Float16* sw8(_Float16* b, int row, int offh){
    int byte = (row<<8) + (offh<<1);
    byte ^= (row&7)<<4;
    return (_Float16*)((char*)b + byte);
}
// ea: row stride 32 f16 (64B), XOR bits 4-5 by row&3.
__device__ __forceinline__ _Float16* swea(_Float16* b, int row, int offh){
    int byte = (row<<6) + (offh<<1);
    byte ^= (row&3)<<4;
    return (_Float16*)((char*)b + byte);
}

#define MFMA(a,b,c) __builtin_amdgcn_mfma_f32_16x16x32_f16((a),(b),(c),0,0,0)

__device__ __forceinline__ f4 z4(){ f4 v; v[0]=0.f; v[1]=0.f; v[2]=0.f; v[3]=0.f; return v; }

// ---- prep: transpose+convert weights f32[K][N] -> f16[N][K], per l ----
__global__ void prep_t(const float* __restrict__ src, _Float16* __restrict__ dst,
                       int K, int N, int total){
    int i = blockIdx.x*256 + threadIdx.x;
    if (i >= total) return;
    int kn = K*N;
    int l = i / kn; int r = i - l*kn;
    int n = r / K;  int k = r - n*K;
    dst[i] = (_Float16)src[(size_t)l*kn + (size_t)k*N + n];
}

// ws layout (f16 element offsets)
constexpr int O_MSG1 = 0;        // 4 x [128][288]
constexpr int O_MSG2 = 147456;   // 4 x [128][128]
constexpr int O_UPD1 = 212992;   // 4 x [128][256]
constexpr int O_UPD2 = 344064;   // 4 x [128][128]
constexpr int O_POOL = 409600;   // [256][640]
constexpr int O_MLP1 = 573440;   // [256][256]
constexpr int O_MLP2 = 638976;   // [64][256]

__global__ __launch_bounds__(512, 4)
void gnn_mfma(const float* __restrict__ nfeat, const float* __restrict__ efeat,
              const int* __restrict__ eidx,
              const float* __restrict__ node_w, const float* __restrict__ node_b,
              const float* __restrict__ edge_w, const float* __restrict__ edge_b,
              const _Float16* __restrict__ wT,
              const float* __restrict__ msg_b1, const float* __restrict__ msg_b2,
              const float* __restrict__ upd_b1, const float* __restrict__ upd_g1, const float* __restrict__ upd_be1,
              const float* __restrict__ upd_b2, const float* __restrict__ upd_g2, const float* __restrict__ upd_be2,
              const float* __restrict__ pool_b, const float* __restrict__ pool_g, const float* __restrict__ pool_be,
              const float* __restrict__ mlp1_b, const float* __restrict__ mlp1_g, const float* __restrict__ mlp1_be,
              const float* __restrict__ mlp2_b, const float* __restrict__ mlp2_g, const float* __restrict__ mlp2_be,
              float* __restrict__ out)
{
    extern __shared__ char smem[];
    _Float16* xh  = (_Float16*)(smem);          // 80 rows x 128, swz8  (20480 B)
    _Float16* ea  = (_Float16*)(smem + 20480);  // 128 rows x 32, swea  ( 8192 B)
    _Float16* buf = (_Float16*)(smem + 28672);  // 128 rows x 128, swz8 (32768 B)
    _Float16* agg = (_Float16*)(smem + 61440);  // 80 rows x 128, swz8  (20480 B)
    float*    miscf = (float*)(smem + 61440);   // alias over agg (encoder stage)
    float*    partf = (float*)(smem + 61440);   // alias over agg (final reduce)

    const int tid  = threadIdx.x;
    const int w    = tid >> 6;
    const int lane = tid & 63;
    const int l15  = lane & 15;
    const int kg   = lane >> 4;          // k-group 0..3
    const int mgM  = w >> 1;             // message-GEMM M-group (2 mtiles of 16)
    const int ngM  = w & 1;              // N-group (64 cols)
    const int mgU  = w >> 1;             // update-GEMM M-group over 5 mtiles
    const int cntU = (mgU < 2) ? 2 : ((mgU == 2) ? 1 : 0);
    const int gbase = blockIdx.x * GG;

    // ---- edge index decode (int32 or int64), packed 4-bit ----
    int dp = 0, sp = 0;
    {
        bool is64 = true;
        #pragma unroll
        for (int i = 1; i < 16; i += 2) if (eidx[i] != 0) is64 = false;
        #pragma unroll
        for (int e = 0; e < 8; ++e){
            int s = is64 ? eidx[2*e]     : eidx[e];
            int d = is64 ? eidx[16+2*e]  : eidx[8+e];
            sp |= s << (4*e); dp |= d << (4*e);
        }
    }
    const int eMine = l15 & 7;
    const int myDst = (dp >> (4*eMine)) & 15;
    const int mySrc = (sp >> (4*eMine)) & 15;

    // ---- encoder: stage nf/ef ----
    for (int i = tid; i < 816; i += 512){
        if (i < 560) miscf[i] = nfeat[(size_t)gbase*35 + i];
        else         miscf[i] = efeat[(size_t)gbase*16 + (i - 560)];
    }
    __syncthreads();

    // ea = ef @ edge_w + edge_b  (f16, 512 h8-units, 1 per thread)
    {
        int u  = tid;
        int ge = u >> 2, c8 = (u & 3) * 8;
        int g  = ge >> 3, e = ge & 7;
        float f0 = miscf[560 + g*16 + e*2];
        float f1 = miscf[560 + g*16 + e*2 + 1];
        h8 v;
        #pragma unroll
        for (int j = 0; j < 8; ++j){
            int c = c8 + j;
            v[j] = (_Float16)(edge_b[c] + f0*edge_w[c] + f1*edge_w[32 + c]);
        }
        *(h8*)swea(ea, ge, c8) = v;
    }

    // x = nf @ node_w + node_b : fp32 regs (ownership = update C-layout) + xh f16
    float xreg[2][4][4];
    #pragma unroll
    for (int mi = 0; mi < 2; ++mi){
        if (mi < cntU){
            int mt = mgU*2 + mi;
            #pragma unroll
            for (int nt = 0; nt < 4; ++nt){
                int col = ngM*64 + nt*16 + l15;
                float w0 = node_w[0*128+col], w1 = node_w[1*128+col],
                      w2 = node_w[2*128+col], w3 = node_w[3*128+col],
                      w4 = node_w[4*128+col], w5 = node_w[5*128+col],
                      w6 = node_w[6*128+col];
                float bb = node_b[col];
                #pragma unroll
                for (int r = 0; r < 4; ++r){
                    int row = mt*16 + kg*4 + r;
                    int g = div5(row), n = row - 5*g;
                    const float* nf = &miscf[g*35 + n*7];
                    float v = bb + nf[0]*w0 + nf[1]*w1 + nf[2]*w2 + nf[3]*w3
                                 + nf[4]*w4 + nf[5]*w5 + nf[6]*w6;
                    xreg[mi][nt][r] = v;
                    *sw8(xh, row, col) = (_Float16)v;
                }
            }
        }
    }
    __syncthreads();

    // ---- 4 message-passing layers ----
    for (int l = 0; l < 4; ++l){
        const _Float16* W1 = wT + O_MSG1 + (size_t)l*36864;
        const _Float16* W2 = wT + O_MSG2 + (size_t)l*16384;
        const _Float16* W3 = wT + O_UPD1 + (size_t)l*32768;
        const _Float16* W4 = wT + O_UPD2 + (size_t)l*16384;

        // ===== GEMM1: m1 = lrelu([x_dst | x_src | ea] @ W1 + b1)  M=128 K=288 N=128
        {
            f4 acc[2][4];
            #pragma unroll
            for (int mi=0;mi<2;++mi){ acc[mi][0]=z4(); acc[mi][1]=z4(); acc[mi][2]=z4(); acc[mi][3]=z4(); }
            int xrow_d[2], xrow_s[2], earow[2];
            #pragma unroll
            for (int mi = 0; mi < 2; ++mi){
                int mt = mgM*2 + mi;
                int g  = mt*2 + (l15 >> 3);
                xrow_d[mi] = g*5 + myDst;
                xrow_s[mi] = g*5 + mySrc;
                earow[mi]  = mt*16 + l15;
            }
            const _Float16* Bp = W1 + (size_t)(ngM*64 + l15)*288 + kg*8;
            #pragma unroll
            for (int kc = 0; kc < 4; ++kc){          // k 0..127 : x[dst]
                h8 b0 = *(const h8*)(Bp + 0*4608 + kc*32);
                h8 b1 = *(const h8*)(Bp + 1*4608 + kc*32);
                h8 b2 = *(const h8*)(Bp + 2*4608 + kc*32);
                h8 b3 = *(const h8*)(Bp + 3*4608 + kc*32);
                #pragma unroll
                for (int mi = 0; mi < 2; ++mi){
                    h8 a = *(const h8*)sw8(xh, xrow_d[mi], kc*32 + kg*8);
                    acc[mi][0]=MFMA(a,b0,acc[mi][0]); acc[mi][1]=MFMA(a,b1,acc[mi][1]);
                    acc[mi][2]=MFMA(a,b2,acc[mi][2]); acc[mi][3]=MFMA(a,b3,acc[mi][3]);
                }
            }
            #pragma unroll
            for (int kc = 0; kc < 4; ++kc){          // k 128..255 : x[src]
                h8 b0 = *(const h8*)(Bp + 0*4608 + 128 + kc*32);
                h8 b1 = *(const h8*)(Bp + 1*4608 + 128 + kc*32);
                h8 b2 = *(const h8*)(Bp + 2*4608 + 128 + kc*32);
                h8 b3 = *(const h8*)(Bp + 3*4608 + 128 + kc*32);
                #pragma unroll
                for (int mi = 0; mi < 2; ++mi){
                    h8 a = *(const h8*)sw8(xh, xrow_s[mi], kc*32 + kg*8);
                    acc[mi][0]=MFMA(a,b0,acc[mi][0]); acc[mi][1]=MFMA(a,b1,acc[mi][1]);
                    acc[mi][2]=MFMA(a,b2,acc[mi][2]); acc[mi][3]=MFMA(a,b3,acc[mi][3]);
                }
            }
            {                                         // k 256..287 : ea
                h8 b0 = *(const h8*)(Bp + 0*4608 + 256);
                h8 b1 = *(const h8*)(Bp + 1*4608 + 256);
                h8 b2 = *(const h8*)(Bp + 2*4608 + 256);
                h8 b3 = *(const h8*)(Bp + 3*4608 + 256);
                #pragma unroll
                for (int mi = 0; mi < 2; ++mi){
                    h8 a = *(const h8*)swea(ea, earow[mi], kg*8);
                    acc[mi][0]=MFMA(a,b0,acc[mi][0]); acc[mi][1]=MFMA(a,b1,acc[mi][1]);
                    acc[mi][2]=MFMA(a,b2,acc[mi][2]); acc[mi][3]=MFMA(a,b3,acc[mi][3]);
                }
            }
            #pragma unroll
            for (int mi = 0; mi < 2; ++mi){
                int mt = mgM*2 + mi;
                #pragma unroll
                for (int nt = 0; nt < 4; ++nt){
                    int col = ngM*64 + nt*16 + l15;
                    float bb = msg_b1[l*128 + col];
                    #pragma unroll
                    for (int r = 0; r < 4; ++r){
                        int row = mt*16 + kg*4 + r;
                        *sw8(buf, row, col) = (_Float16)lrelu(acc[mi][nt][r] + bb);
                    }
                }
            }
        }
        __syncthreads();

        // ===== GEMM2: m2 = lrelu(m1 @ W2 + b2)  M=128 K=128 N=128 (acc in regs)
        {
            f4 acc[2][4];
            #pragma unroll
            for (int mi=0;mi<2;++mi){ acc[mi][0]=z4(); acc[mi][1]=z4(); acc[mi][2]=z4(); acc[mi][3]=z4(); }
            const _Float16* Bp = W2 + (size_t)(ngM*64 + l15)*128 + kg*8;
            #pragma unroll
            for (int kc = 0; kc < 4; ++kc){
                h8 b0 = *(const h8*)(Bp + 0*2048 + kc*32);
                h8 b1 = *(const h8*)(Bp + 1*2048 + kc*32);
                h8 b2 = *(const h8*)(Bp + 2*2048 + kc*32);
                h8 b3 = *(const h8*)(Bp + 3*2048 + kc*32);
                #pragma unroll
                for (int mi = 0; mi < 2; ++mi){
                    int arow = (mgM*2+mi)*16 + l15;
                    h8 a = *(const h8*)sw8(buf, arow, kc*32 + kg*8);
                    acc[mi][0]=MFMA(a,b0,acc[mi][0]); acc[mi][1]=MFMA(a,b1,acc[mi][1]);
                    acc[mi][2]=MFMA(a,b2,acc[mi][2]); acc[mi][3]=MFMA(a,b3,acc[mi][3]);
                }
            }
            __syncthreads();   // all m1 reads done before overwrite
            #pragma unroll
            for (int mi = 0; mi < 2; ++mi){
                int mt = mgM*2 + mi;
                #pragma unroll
                for (int nt = 0; nt < 4; ++nt){
                    int col = ngM*64 + nt*16 + l15;
                    float bb = msg_b2[l*128 + col];
                    #pragma unroll
                    for (int r = 0; r < 4; ++r){
                        int row = mt*16 + kg*4 + r;
                        *sw8(buf, row, col) = (_Float16)lrelu(acc[mi][nt][r] + bb);
                    }
                }
            }
        }
        __syncthreads();

        // ===== agg[n] = sum_{e: dst[e]==n} m2[e]   (1280 h8-units)
        for (int u = tid; u < 1280; u += 512){
            int gn = u >> 4, c8 = (u & 15)*8;
            int g = div5(gn), n = gn - 5*g;
            float s0=0,s1=0,s2=0,s3=0,s4=0,s5=0,s6=0,s7=0;
            #pragma unroll
            for (int e = 0; e < 8; ++e){
                if (((dp >> (4*e)) & 15) == n){
                    h8 v = *(const h8*)sw8(buf, g*8 + e, c8);
                    s0+=(float)v[0]; s1+=(float)v[1]; s2+=(float)v[2]; s3+=(float)v[3];
                    s4+=(float)v[4]; s5+=(float)v[5]; s6+=(float)v[6]; s7+=(float)v[7];
                }
            }
            h8 o;
            o[0]=(_Float16)s0; o[1]=(_Float16)s1; o[2]=(_Float16)s2; o[3]=(_Float16)s3;
            o[4]=(_Float16)s4; o[5]=(_Float16)s5; o[6]=(_Float16)s6; o[7]=(_Float16)s7;
            *(h8*)sw8(agg, gn, c8) = o;
        }
        __syncthreads();

        // ===== GEMM3: u1 = lrelu(([x|agg]@W3 + b)*g1[n] + be1[n])  M=80 K=256 N=128
        if (cntU > 0){
            f4 acc[2][4];
            #pragma unroll
            for (int mi=0;mi<2;++mi){ acc[mi][0]=z4(); acc[mi][1]=z4(); acc[mi][2]=z4(); acc[mi][3]=z4(); }
            const _Float16* Bp = W3 + (size_t)(ngM*64 + l15)*256 + kg*8;
            #pragma unroll
            for (int kc = 0; kc < 8; ++kc){
                h8 b0 = *(const h8*)(Bp + 0*4096 + kc*32);
                h8 b1 = *(const h8*)(Bp + 1*4096 + kc*32);
                h8 b2 = *(const h8*)(Bp + 2*4096 + kc*32);
                h8 b3 = *(const h8*)(Bp + 3*4096 + kc*32);
                #pragma unroll
                for (int mi = 0; mi < 2; ++mi){
                    if (mi < cntU){
                        int arow = (mgU*2+mi)*16 + l15;
                        h8 a;
                        if (kc < 4) a = *(const h8*)sw8(xh,  arow, kc*32 + kg*8);
                        else        a = *(const h8*)sw8(agg, arow, (kc-4)*32 + kg*8);
                        acc[mi][0]=MFMA(a,b0,acc[mi][0]); acc[mi][1]=MFMA(a,b1,acc[mi][1]);
                        acc[mi][2]=MFMA(a,b2,acc[mi][2]); acc[mi][3]=MFMA(a,b3,acc[mi][3]);
                    }
                }
            }
            #pragma unroll
            for (int mi = 0; mi < 2; ++mi){
                if (mi < cntU){
                    int mt = mgU*2 + mi;
                    #pragma unroll
                    for (int nt = 0; nt < 4; ++nt){
                        int col = ngM*64 + nt*16 + l15;
                        float bb = upd_b1[l*128 + col];
                        #pragma unroll
                        for (int r = 0; r < 4; ++r){
                            int crow = mt*16 + kg*4 + r;
                            int n = crow - 5*div5(crow);
                            float val = lrelu((acc[mi][nt][r] + bb)*upd_g1[l*5+n] + upd_be1[l*5+n]);
                            *sw8(buf, crow, col) = (_Float16)val;
                        }
                    }
                }
            }
        }
        __syncthreads();

        // ===== GEMM4: x += lrelu((u1@W4 + b)*g2[n] + be2[n])  M=80 K=128 N=128
        if (cntU > 0){
            f4 acc[2][4];
            #pragma unroll
            for (int mi=0;mi<2;++mi){ acc[mi][0]=z4(); acc[mi][1]=z4(); acc[mi][2]=z4(); acc[mi][3]=z4(); }
            const _Float16* Bp = W4 + (size_t)(ngM*64 + l15)*128 + kg*8;
            #pragma unroll
            for (int kc = 0; kc < 4; ++kc){
                h8 b0 = *(const h8*)(Bp + 0*2048 + kc*32);
                h8 b1 = *(const h8*)(Bp + 1*2048 + kc*32);
                h8 b2 = *(const h8*)(Bp + 2*2048 + kc*32);
                h8 b3 = *(const h8*)(Bp + 3*2048 + kc*32);
                #pragma unroll
                for (int mi = 0; mi < 2; ++mi){
                    if (mi < cntU){
                        int arow = (mgU*2+mi)*16 + l15;
                        h8 a = *(const h8*)sw8(buf, arow, kc*32 + kg*8);
                        acc[mi][0]=MFMA(a,b0,acc[mi][0]); acc[mi][1]=MFMA(a,b1,acc[mi][1]);
                        acc[mi][2]=MFMA(a,b2,acc[mi][2]); acc[mi][3]=MFMA(a,b3,acc[mi][3]);
                    }
                }
            }
            #pragma unroll
            for (int mi = 0; mi < 2; ++mi){
                if (mi < cntU){
                    int mt = mgU*2 + mi;
                    #pragma unroll
                    for (int nt = 0; nt < 4; ++nt){
                        int col = ngM*64 + nt*16 + l15;
                        float bb = upd_b2[l*128 + col];
                        #pragma unroll
                        for (int r = 0; r < 4; ++r){
                            int crow = mt*16 + kg*4 + r;
                            int n = crow - 5*div5(crow);
                            float val = lrelu((acc[mi][nt][r] + bb)*upd_g2[l*5+n] + upd_be2[l*5+n]);
                            xreg[mi][nt][r] += val;
                            *sw8(xh, crow, col) = (_Float16)xreg[mi][nt][r];
                        }
                    }
                }
            }
        }
        __syncthreads();
    }

    // ===== pool: p = lrelu((x.flat @ poolW + b)*g + be)  M=16 K=640 N=256
    {
        f4 accP[2]; accP[0]=z4(); accP[1]=z4();
        const _Float16* Bp = wT + O_POOL + (size_t)(w*32 + l15)*640 + kg*8;
        #pragma unroll
        for (int kc = 0; kc < 20; ++kc){
            int k0 = kc*32 + kg*8;
            int n  = k0 >> 7, d = k0 & 127;
            h8 a  = *(const h8*)sw8(xh, l15*5 + n, d);
            h8 b0 = *(const h8*)(Bp + kc*32);
            h8 b1 = *(const h8*)(Bp + 16*640 + kc*32);
            accP[0]=MFMA(a,b0,accP[0]); accP[1]=MFMA(a,b1,accP[1]);
        }
        #pragma unroll
        for (int nt = 0; nt < 2; ++nt){
            int col = w*32 + nt*16 + l15;
            float pb = pool_b[col], pg = pool_g[col], pe = pool_be[col];
            #pragma unroll
            for (int r = 0; r < 4; ++r){
                int g = kg*4 + r;
                float val = lrelu((accP[nt][r] + pb)*pg + pe);
                int prow = g + 16*(col >> 7);
                *sw8(buf, prow, col & 127) = (_Float16)val;
            }
        }
    }
    __syncthreads();

    // ===== mlp1: q = lrelu((p@W + b)*g + be)  M=16 K=256 N=256
    {
        f4 accQ[2]; accQ[0]=z4(); accQ[1]=z4();
        const _Float16* Bp = wT + O_MLP1 + (size_t)(w*32 + l15)*256 + kg*8;
        #pragma unroll
        for (int kc = 0; kc < 8; ++kc){
            int k0 = kc*32 + kg*8;
            int arow = l15 + 16*(k0 >> 7);
            h8 a  = *(const h8*)sw8(buf, arow, k0 & 127);
            h8 b0 = *(const h8*)(Bp + kc*32);
            h8 b1 = *(const h8*)(Bp + 16*256 + kc*32);
            accQ[0]=MFMA(a,b0,accQ[0]); accQ[1]=MFMA(a,b1,accQ[1]);
        }
        __syncthreads();   // p reads done before q writes share region? (disjoint rows, but order anyway)
        #pragma unroll
        for (int nt = 0; nt < 2; ++nt){
            int col = w*32 + nt*16 + l15;
            float qb = mlp1_b[col], qg = mlp1_g[col], qe = mlp1_be[col];
            #pragma unroll
            for (int r = 0; r < 4; ++r){
                int g = kg*4 + r;
                float val = lrelu((accQ[nt][r] + qb)*qg + qe);
                int qrow = 32 + g + 16*(col >> 7);
                *sw8(buf, qrow, col & 127) = (_Float16)val;
            }
        }
    }
    __syncthreads();

    // ===== mlp2 + mean: M=16 K=256 N=64 (waves 0-3), then reduce over 64 cols
    if (w < 4){
        f4 accR = z4();
        const _Float16* Bp = wT + O_MLP2 + (size_t)(w*16 + l15)*256 + kg*8;
        #pragma unroll
        for (int kc = 0; kc < 8; ++kc){
            int k0 = kc*32 + kg*8;
            int arow = 32 + l15 + 16*(k0 >> 7);
            h8 a = *(const h8*)sw8(buf, arow, k0 & 127);
            h8 b = *(const h8*)(Bp + kc*32);
            accR = MFMA(a, b, accR);
        }
        int col = w*16 + l15;
        float rb = mlp2_b[col], rg = mlp2_g[col], re = mlp2_be[col];
        #pragma unroll
        for (int r = 0; r < 4; ++r){
            float val = lrelu((accR[r] + rb)*rg + re);
            val += __shfl_xor(val, 1);
            val += __shfl_xor(val, 2);
            val += __shfl_xor(val, 4);
            val += __shfl_xor(val, 8);
            if (l15 == 0) partf[w*16 + (kg*4 + r)] = val;
        }
    }
    __syncthreads();
    if (tid < 16){
        float s = partf[tid] + partf[16+tid] + partf[32+tid] + partf[48+tid];
        out[gbase + tid] = s * (1.0f/64.0f);
    }
}

extern "C" void kernel_launch(void* const* d_in, const int* in_sizes, int n_in,
                              void* d_out, int out_size, void* d_ws, size_t ws_size,
                              hipStream_t stream) {
    _Float16* wT = (_Float16*)d_ws;
    auto T = [&](const void* src, int dstoff, int L, int K, int N){
        int total = L*K*N;
        prep_t<<<(total + 255)/256, 256, 0, stream>>>((const float*)src, wT + dstoff, K, N, total);
    };
    T(d_in[7],  O_MSG1, 4, 288, 128);
    T(d_in[9],  O_MSG2, 4, 128, 128);
    T(d_in[11], O_UPD1, 4, 256, 128);
    T(d_in[15], O_UPD2, 4, 128, 128);
    T(d_in[19], O_POOL, 1, 640, 256);
    T(d_in[23], O_MLP1, 1, 256, 256);
    T(d_in[27], O_MLP2, 1, 256, 64);

    gnn_mfma<<<NBLK, 512, 81920, stream>>>(
        (const float*)d_in[0], (const float*)d_in[1], (const int*)d_in[2],
        (const float*)d_in[3], (const float*)d_in[4],
        (const float*)d_in[5], (const float*)d_in[6],
        wT,
        (const float*)d_in[8],  (const float*)d_in[10],
        (const float*)d_in[12], (const float*)d_in[13], (const float*)d_in[14],
        (const float*)d_in[16], (const float*)d_in[17], (const float*)d_in[18],
        (const float*)d_in[20], (const float*)d_in[21], (const float*)d_in[22],
        (const float*)d_in[24], (const float*)d_in[25], (const float*)d_in[26],
        (const float*)d_in[28], (const float*)d_in[29], (const float*)d_in[30],
        (float*)d_out);
}